// Round 4
// baseline (90.883 us; speedup 1.0000x reference)
//
#include <hip/hip_runtime.h>
#include <math.h>

// ExpertGating: h=relu(hs@W1+b1); logits=h@W2+b2; softmax; top-2; combine.
// R4: same as R3 design; fixed the LDS pointer-array static-initializer compile
// error by using a static __shared__ block and integer offset arithmetic.
//   GEMM1 = split-bf16 3-pass MFMA, 256x128 tile, BK=32, 8 waves,
//   double-buffered 96KB LDS, counted s_waitcnt vmcnt(6), raw s_barrier,
//   setprio around MFMA clusters. Fragment/image layout identical to R2 (verified).

#define H_DIM 1024
#define E_NUM 8

typedef __attribute__((ext_vector_type(8))) short s16x8;
typedef __attribute__((ext_vector_type(8))) unsigned short u16x8;
typedef __attribute__((ext_vector_type(4))) float f32x4;

__device__ __forceinline__ unsigned short f2bf(float x) {
    unsigned int u = __float_as_uint(x);
    unsigned int r = (u + 0x7FFFu + ((u >> 16) & 1u)) >> 16;
    return (unsigned short)r;
}
__device__ __forceinline__ float bf2f(unsigned short b) {
    return __uint_as_float(((unsigned int)b) << 16);
}
__device__ __forceinline__ void gload_lds16(const void* g, void* lds) {
    __builtin_amdgcn_global_load_lds(
        (const __attribute__((address_space(1))) void*)g,
        (__attribute__((address_space(3))) void*)lds, 16, 0, 0);
}

// ---------------- fused prep: hs and W1 -> swizzled hi/lo bf16 images --------
// Image tile = 128 rows x 128 B (8 slots of 16B: slots 0-3 hi k-octets, 4-7 lo),
// logical slot s stored at physical slot s ^ (row&7). A: [rb(64)][kt(32)] tiles.
// B (W1^T): [cb(8)][kt(32)] tiles, tile row = output col n.
__global__ __launch_bounds__(256) void prep_fused_kernel(
    const float* __restrict__ A, const float* __restrict__ W,
    char* __restrict__ Aimg, char* __restrict__ Bimg)
{
    if (blockIdx.x < 4096) {
        int t = blockIdx.x * 256 + threadIdx.x;   // 8192 rows x 128 octets
        int m = t >> 7;
        int k = (t & 127) << 3;
        const float* src = A + ((size_t)m << 10) + k;
        float4 v0 = *reinterpret_cast<const float4*>(src);
        float4 v1 = *reinterpret_cast<const float4*>(src + 4);
        float xs[8] = {v0.x, v0.y, v0.z, v0.w, v1.x, v1.y, v1.z, v1.w};
        u16x8 hv, lv;
        #pragma unroll
        for (int j = 0; j < 8; ++j) {
            unsigned short h = f2bf(xs[j]);
            hv[j] = h;
            lv[j] = f2bf(xs[j] - bf2f(h));
        }
        int rb = m >> 7, mr = m & 127, kt = k >> 5, s = (k >> 3) & 3;
        char* base = Aimg + (((size_t)(rb * 32 + kt)) << 14) + mr * 128;
        *reinterpret_cast<u16x8*>(base + ((s ^ (mr & 7)) << 4)) = hv;
        *reinterpret_cast<u16x8*>(base + (((s + 4) ^ (mr & 7)) << 4)) = lv;
    } else {
        int t = (blockIdx.x - 4096) * 256 + threadIdx.x;  // 1024 cols x 128 octets
        int n = t & 1023;
        int k = (t >> 10) << 3;
        u16x8 hv, lv;
        #pragma unroll
        for (int j = 0; j < 8; ++j) {
            float x = W[((size_t)(k + j) << 10) + n];
            unsigned short h = f2bf(x);
            hv[j] = h;
            lv[j] = f2bf(x - bf2f(h));
        }
        int cb = n >> 7, nr = n & 127, kt = k >> 5, s = (k >> 3) & 3;
        char* base = Bimg + (((size_t)(cb * 32 + kt)) << 14) + nr * 128;
        *reinterpret_cast<u16x8*>(base + ((s ^ (nr & 7)) << 4)) = hv;
        *reinterpret_cast<u16x8*>(base + (((s + 4) ^ (nr & 7)) << 4)) = lv;
    }
}

// ---------------- GEMM1: 256x128 tile, BK=32, 8 waves, pipelined ----------------
#define MFMA_B16 __builtin_amdgcn_mfma_f32_16x16x32_bf16

__global__ __launch_bounds__(512, 2) void gemm1_mfma8_kernel(
    const char* __restrict__ Aimg, const char* __restrict__ Bimg,
    const float* __restrict__ bias, float* __restrict__ Hout)
{
    __shared__ char smem[98304];   // A: 2 x 32KB at 0/32768; B: 2 x 16KB at 65536/81920

    const int bid = blockIdx.x;
    const int swz = (bid & 7) * 32 + (bid >> 3);   // bijective, 256 % 8 == 0
    const int rb2 = swz >> 3;    // 0..31  (rows rb2*256 .. +255)
    const int cb  = swz & 7;     // 0..7   (cols cb*128 .. +127)

    const int tid = threadIdx.x;
    const int lane = tid & 63;
    const int wave = tid >> 6;           // 0..7
    const int wm = (wave >> 1) * 64;     // 0,64,128,192
    const int wn = (wave & 1) * 64;      // 0,64
    const int l15 = lane & 15, l4 = lane >> 4;
    const int toff = tid << 4;           // 0..8191

    // fragment LDS offsets (swizzle baked in), constant across K-tiles
    int aoff_h[4], aoff_l[4], boff_h[4], boff_l[4];
    #pragma unroll
    for (int f = 0; f < 4; ++f) {
        int ar = wm + f * 16 + l15;                       // 0..255
        aoff_h[f] = ((ar >> 7) << 14) + (ar & 127) * 128 + ((l4 ^ (ar & 7)) << 4);
        aoff_l[f] = ((ar >> 7) << 14) + (ar & 127) * 128 + (((l4 + 4) ^ (ar & 7)) << 4);
        int br = wn + f * 16 + l15;                       // 0..127
        boff_h[f] = br * 128 + ((l4 ^ (br & 7)) << 4);
        boff_l[f] = br * 128 + (((l4 + 4) ^ (br & 7)) << 4);
    }

    const char* gA = Aimg + (((size_t)(rb2 * 2) * 32) << 14);  // row-blocks 2*rb2, 2*rb2+1
    const char* gB = Bimg + (((size_t)cb * 32) << 14);

#define STAGE(aOfs, bOfs, kt_) do {                                                         \
    gload_lds16(gA + (((size_t)(kt_)) << 14) + toff,            smem + (aOfs) + toff);          \
    gload_lds16(gA + (((size_t)(kt_)) << 14) + 8192 + toff,     smem + (aOfs) + 8192 + toff);   \
    gload_lds16(gA + (((size_t)(32 + (kt_))) << 14) + toff,         smem + (aOfs) + 16384 + toff); \
    gload_lds16(gA + (((size_t)(32 + (kt_))) << 14) + 8192 + toff,  smem + (aOfs) + 24576 + toff); \
    gload_lds16(gB + (((size_t)(kt_)) << 14) + toff,            smem + (bOfs) + toff);          \
    gload_lds16(gB + (((size_t)(kt_)) << 14) + 8192 + toff,     smem + (bOfs) + 8192 + toff);   \
} while (0)

    f32x4 acc[4][4];
    #pragma unroll
    for (int i = 0; i < 4; ++i)
        #pragma unroll
        for (int j = 0; j < 4; ++j)
            acc[i][j] = (f32x4){0.f, 0.f, 0.f, 0.f};

    STAGE(0, 65536, 0);   // prologue: tile 0 -> buf0

    for (int kt = 0; kt < 32; ++kt) {
        const int cur = kt & 1;
        const int aO = cur * 32768;
        const int bO = 65536 + cur * 16384;
        const char* curA = smem + aO;
        const char* curB = smem + bO;
        if (kt < 31) {
            STAGE(aO ^ 32768, (bO ^ 16384), kt + 1);   // prefetch next tile
            asm volatile("s_waitcnt vmcnt(6)" ::: "memory");  // tile-kt landed; 6 in flight
        } else {
            asm volatile("s_waitcnt vmcnt(0)" ::: "memory");
        }
        asm volatile("s_barrier" ::: "memory");        // all waves' tile-kt loads landed

        // ---- sub-phase 0: read all B frags + A rows 0,1; MFMA m=0,1 ----
        s16x8 bh[4], bl[4];
        #pragma unroll
        for (int f = 0; f < 4; ++f) {
            bh[f] = *reinterpret_cast<const s16x8*>(curB + boff_h[f]);
            bl[f] = *reinterpret_cast<const s16x8*>(curB + boff_l[f]);
        }
        s16x8 a0h = *reinterpret_cast<const s16x8*>(curA + aoff_h[0]);
        s16x8 a0l = *reinterpret_cast<const s16x8*>(curA + aoff_l[0]);
        s16x8 a1h = *reinterpret_cast<const s16x8*>(curA + aoff_h[1]);
        s16x8 a1l = *reinterpret_cast<const s16x8*>(curA + aoff_l[1]);
        asm volatile("s_barrier" ::: "memory");
        __builtin_amdgcn_s_setprio(1);
        #pragma unroll
        for (int n = 0; n < 4; ++n) {
            acc[0][n] = MFMA_B16(a0h, bh[n], acc[0][n], 0, 0, 0);
            acc[0][n] = MFMA_B16(a0h, bl[n], acc[0][n], 0, 0, 0);
            acc[0][n] = MFMA_B16(a0l, bh[n], acc[0][n], 0, 0, 0);
            acc[1][n] = MFMA_B16(a1h, bh[n], acc[1][n], 0, 0, 0);
            acc[1][n] = MFMA_B16(a1h, bl[n], acc[1][n], 0, 0, 0);
            acc[1][n] = MFMA_B16(a1l, bh[n], acc[1][n], 0, 0, 0);
        }
        __builtin_amdgcn_s_setprio(0);
        asm volatile("s_barrier" ::: "memory");

        // ---- sub-phase 1: read A rows 2,3; MFMA m=2,3 (B stays in regs) ----
        s16x8 a2h = *reinterpret_cast<const s16x8*>(curA + aoff_h[2]);
        s16x8 a2l = *reinterpret_cast<const s16x8*>(curA + aoff_l[2]);
        s16x8 a3h = *reinterpret_cast<const s16x8*>(curA + aoff_h[3]);
        s16x8 a3l = *reinterpret_cast<const s16x8*>(curA + aoff_l[3]);
        asm volatile("s_barrier" ::: "memory");
        __builtin_amdgcn_s_setprio(1);
        #pragma unroll
        for (int n = 0; n < 4; ++n) {
            acc[2][n] = MFMA_B16(a2h, bh[n], acc[2][n], 0, 0, 0);
            acc[2][n] = MFMA_B16(a2h, bl[n], acc[2][n], 0, 0, 0);
            acc[2][n] = MFMA_B16(a2l, bh[n], acc[2][n], 0, 0, 0);
            acc[3][n] = MFMA_B16(a3h, bh[n], acc[3][n], 0, 0, 0);
            acc[3][n] = MFMA_B16(a3h, bl[n], acc[3][n], 0, 0, 0);
            acc[3][n] = MFMA_B16(a3l, bh[n], acc[3][n], 0, 0, 0);
        }
        __builtin_amdgcn_s_setprio(0);
        asm volatile("s_barrier" ::: "memory");
    }
#undef STAGE

    // epilogue: bias + relu. C/D map: row=(lane>>4)*4+reg, col=lane&15 (verified R2)
    const int row0 = rb2 * 256 + wm;
    const int col0 = cb * 128 + wn;
    float bcol[4];
    #pragma unroll
    for (int fn = 0; fn < 4; ++fn) bcol[fn] = bias[col0 + fn * 16 + l15];
    #pragma unroll
    for (int fm = 0; fm < 4; ++fm)
        #pragma unroll
        for (int r = 0; r < 4; ++r) {
            int row = row0 + fm * 16 + l4 * 4 + r;
            float* orow = Hout + ((size_t)row << 10);
            #pragma unroll
            for (int fn = 0; fn < 4; ++fn) {
                int col = col0 + fn * 16 + l15;
                orow[col] = fmaxf(acc[fm][fn][r] + bcol[fn], 0.f);
            }
        }
}

// ---------------- R1 fallback fp32 SGEMM (verified) ----------------
#define BM 128
#define BN 128
#define BK 16
#define PAD_LD 132

__global__ __launch_bounds__(256) void gemm1_relu_kernel(
    const float* __restrict__ A, const float* __restrict__ W,
    const float* __restrict__ bias, float* __restrict__ Hout,
    int M, int N, int K)
{
    __shared__ float As[BK][PAD_LD];
    __shared__ float Bs[BK][PAD_LD];
    const int tid = threadIdx.x;
    const int tx = tid & 15;
    const int ty = tid >> 4;
    const int row0 = blockIdx.y * BM;
    const int col0 = blockIdx.x * BN;
    float acc[8][8];
    #pragma unroll
    for (int i = 0; i < 8; ++i)
        #pragma unroll
        for (int j = 0; j < 8; ++j) acc[i][j] = 0.f;
    const int a_row = tid >> 2;
    const int a_k4  = (tid & 3) * 4;
    const int b_col4 = (tid & 31) * 4;
    const int b_kk   = tid >> 5;
    for (int k0 = 0; k0 < K; k0 += BK) {
        #pragma unroll
        for (int half = 0; half < 2; ++half) {
            int r = a_row + half * 64;
            float4 av = *reinterpret_cast<const float4*>(&A[(size_t)(row0 + r) * K + k0 + a_k4]);
            As[a_k4 + 0][r] = av.x; As[a_k4 + 1][r] = av.y;
            As[a_k4 + 2][r] = av.z; As[a_k4 + 3][r] = av.w;
        }
        #pragma unroll
        for (int half = 0; half < 2; ++half) {
            int kk = b_kk + half * 8;
            float4 bv = *reinterpret_cast<const float4*>(&W[(size_t)(k0 + kk) * N + col0 + b_col4]);
            *reinterpret_cast<float4*>(&Bs[kk][b_col4]) = bv;
        }
        __syncthreads();
        #pragma unroll
        for (int k = 0; k < BK; ++k) {
            float4 a0 = *reinterpret_cast<const float4*>(&As[k][ty * 8]);
            float4 a1 = *reinterpret_cast<const float4*>(&As[k][ty * 8 + 4]);
            float4 b0 = *reinterpret_cast<const float4*>(&Bs[k][tx * 8]);
            float4 b1 = *reinterpret_cast<const float4*>(&Bs[k][tx * 8 + 4]);
            float a[8] = {a0.x, a0.y, a0.z, a0.w, a1.x, a1.y, a1.z, a1.w};
            float b[8] = {b0.x, b0.y, b0.z, b0.w, b1.x, b1.y, b1.z, b1.w};
            #pragma unroll
            for (int i = 0; i < 8; ++i)
                #pragma unroll
                for (int j = 0; j < 8; ++j)
                    acc[i][j] = fmaf(a[i], b[j], acc[i][j]);
        }
        __syncthreads();
    }
    #pragma unroll
    for (int i = 0; i < 8; ++i) {
        int row = row0 + ty * 8 + i;
        #pragma unroll
        for (int j4 = 0; j4 < 2; ++j4) {
            int col = col0 + tx * 8 + j4 * 4;
            float4 v;
            v.x = fmaxf(acc[i][j4 * 4 + 0] + bias[col + 0], 0.f);
            v.y = fmaxf(acc[i][j4 * 4 + 1] + bias[col + 1], 0.f);
            v.z = fmaxf(acc[i][j4 * 4 + 2] + bias[col + 2], 0.f);
            v.w = fmaxf(acc[i][j4 * 4 + 3] + bias[col + 3], 0.f);
            *reinterpret_cast<float4*>(&Hout[(size_t)row * N + col]) = v;
        }
    }
}

// ---------------- router + combine (one block per token) ----------------
__global__ __launch_bounds__(256) void route_combine_kernel(
    const float* __restrict__ Hbuf, const float* __restrict__ W2,
    const float* __restrict__ b2, const float* __restrict__ EO,
    float* __restrict__ Out, int M)
{
    const int t = blockIdx.x;
    const int tid = threadIdx.x;
    const int lane = tid & 63;
    const int wave = tid >> 6;
    const float* hrow = Hbuf + (size_t)t * H_DIM;

    float part[E_NUM];
    #pragma unroll
    for (int e = 0; e < E_NUM; ++e) part[e] = 0.f;
    #pragma unroll
    for (int it = 0; it < H_DIM / 256; ++it) {
        int j = tid + it * 256;
        float hv = hrow[j];
        const float* w = W2 + (size_t)j * E_NUM;
        #pragma unroll
        for (int e = 0; e < E_NUM; ++e) part[e] = fmaf(hv, w[e], part[e]);
    }
    #pragma unroll
    for (int off = 32; off > 0; off >>= 1)
        #pragma unroll
        for (int e = 0; e < E_NUM; ++e)
            part[e] += __shfl_down(part[e], off, 64);

    __shared__ float sred[4][E_NUM];
    __shared__ float s_g[2];
    __shared__ int   s_e[2];
    if (lane == 0)
        #pragma unroll
        for (int e = 0; e < E_NUM; ++e) sred[wave][e] = part[e];
    __syncthreads();

    if (tid == 0) {
        float logits[E_NUM];
        #pragma unroll
        for (int e = 0; e < E_NUM; ++e)
            logits[e] = sred[0][e] + sred[1][e] + sred[2][e] + sred[3][e] + b2[e];
        float m = logits[0];
        #pragma unroll
        for (int e = 1; e < E_NUM; ++e) m = fmaxf(m, logits[e]);
        float p[E_NUM], ssum = 0.f;
        #pragma unroll
        for (int e = 0; e < E_NUM; ++e) { p[e] = expf(logits[e] - m); ssum += p[e]; }
        float inv = 1.f / ssum;
        #pragma unroll
        for (int e = 0; e < E_NUM; ++e) p[e] *= inv;
        int e0 = 0;
        #pragma unroll
        for (int e = 1; e < E_NUM; ++e) if (p[e] > p[e0]) e0 = e;
        int e1 = (e0 == 0) ? 1 : 0;
        #pragma unroll
        for (int e = 0; e < E_NUM; ++e)
            if (e != e0 && e != e1 && p[e] > p[e1]) e1 = e;
        s_g[0] = p[e0]; s_g[1] = p[e1];
        s_e[0] = e0;    s_e[1] = e1;
    }
    __syncthreads();

    const float g0 = s_g[0], g1 = s_g[1];
    const size_t base0 = ((size_t)s_e[0] * M + t) * H_DIM;
    const size_t base1 = ((size_t)s_e[1] * M + t) * H_DIM;
    const int d = tid * 4;
    float4 x0 = *reinterpret_cast<const float4*>(&EO[base0 + d]);
    float4 x1 = *reinterpret_cast<const float4*>(&EO[base1 + d]);
    float4 o;
    o.x = g0 * x0.x + g1 * x1.x;
    o.y = g0 * x0.y + g1 * x1.y;
    o.z = g0 * x0.z + g1 * x1.z;
    o.w = g0 * x0.w + g1 * x1.w;
    *reinterpret_cast<float4*>(&Out[(size_t)t * H_DIM + d]) = o;
}

extern "C" void kernel_launch(void* const* d_in, const int* in_sizes, int n_in,
                              void* d_out, int out_size, void* d_ws, size_t ws_size,
                              hipStream_t stream)
{
    const float* hs = (const float*)d_in[0];
    const float* EO = (const float*)d_in[1];
    const float* W1 = (const float*)d_in[2];
    const float* b1 = (const float*)d_in[3];
    const float* W2 = (const float*)d_in[4];
    const float* b2 = (const float*)d_in[5];

    const int M = in_sizes[0] / H_DIM;   // 8192
    float* out = (float*)d_out;

    const size_t A_IMG = (size_t)64 * 32 * 16384;
    const size_t B_IMG = (size_t)8 * 32 * 16384;
    if (M == 8192 && ws_size >= A_IMG + B_IMG) {
        char* Aimg = (char*)d_ws;
        char* Bimg = (char*)d_ws + A_IMG;
        prep_fused_kernel<<<4096 + 512, 256, 0, stream>>>(hs, W1, Aimg, Bimg);
        gemm1_mfma8_kernel<<<256, 512, 0, stream>>>(Aimg, Bimg, b1, out);
    } else {
        dim3 grid1(H_DIM / BN, M / BM);
        gemm1_relu_kernel<<<grid1, 256, 0, stream>>>(hs, W1, b1, out, M, H_DIM, H_DIM);
    }
    route_combine_kernel<<<M, 256, 0, stream>>>(out, W2, b2, EO, out, M);
}

// Round 5
// 86.556 us; speedup vs baseline: 1.0500x; 1.0500x over previous
//
#include <hip/hip_runtime.h>
#include <math.h>

// ExpertGating: h=relu(hs@W1+b1); logits=h@W2+b2; softmax; top-2; combine.
// R5: revert to the R2 (m97-shape) GEMM which measured best; the experiment is
// occupancy: __launch_bounds__(256,3) -> 3 blocks/CU (12 waves/CU, m97's point)
// vs R2's 2. Plus pass-major MFMA ordering (16 independent MFMAs between
// same-accumulator reuses). Fused prep kept from R4.

#define H_DIM 1024
#define E_NUM 8

typedef __attribute__((ext_vector_type(8))) short s16x8;
typedef __attribute__((ext_vector_type(8))) unsigned short u16x8;
typedef __attribute__((ext_vector_type(4))) float f32x4;

__device__ __forceinline__ unsigned short f2bf(float x) {
    unsigned int u = __float_as_uint(x);
    unsigned int r = (u + 0x7FFFu + ((u >> 16) & 1u)) >> 16;
    return (unsigned short)r;
}
__device__ __forceinline__ float bf2f(unsigned short b) {
    return __uint_as_float(((unsigned int)b) << 16);
}
__device__ __forceinline__ void gload_lds16(const void* g, void* lds) {
    __builtin_amdgcn_global_load_lds(
        (const __attribute__((address_space(1))) void*)g,
        (__attribute__((address_space(3))) void*)lds, 16, 0, 0);
}

// ---------------- fused prep: hs and W1 -> swizzled hi/lo bf16 images --------
// Image tile = 128 rows x 128 B (8 slots of 16B: slots 0-3 hi k-octets, 4-7 lo),
// logical slot s stored at physical slot s ^ (row&7). A: [rb(64)][kt(32)] tiles.
// B (W1^T): [cb(8)][kt(32)] tiles, tile row = output col n.
__global__ __launch_bounds__(256) void prep_fused_kernel(
    const float* __restrict__ A, const float* __restrict__ W,
    char* __restrict__ Aimg, char* __restrict__ Bimg)
{
    if (blockIdx.x < 4096) {
        int t = blockIdx.x * 256 + threadIdx.x;   // 8192 rows x 128 octets
        int m = t >> 7;
        int k = (t & 127) << 3;
        const float* src = A + ((size_t)m << 10) + k;
        float4 v0 = *reinterpret_cast<const float4*>(src);
        float4 v1 = *reinterpret_cast<const float4*>(src + 4);
        float xs[8] = {v0.x, v0.y, v0.z, v0.w, v1.x, v1.y, v1.z, v1.w};
        u16x8 hv, lv;
        #pragma unroll
        for (int j = 0; j < 8; ++j) {
            unsigned short h = f2bf(xs[j]);
            hv[j] = h;
            lv[j] = f2bf(xs[j] - bf2f(h));
        }
        int rb = m >> 7, mr = m & 127, kt = k >> 5, s = (k >> 3) & 3;
        char* base = Aimg + (((size_t)(rb * 32 + kt)) << 14) + mr * 128;
        *reinterpret_cast<u16x8*>(base + ((s ^ (mr & 7)) << 4)) = hv;
        *reinterpret_cast<u16x8*>(base + (((s + 4) ^ (mr & 7)) << 4)) = lv;
    } else {
        int t = (blockIdx.x - 4096) * 256 + threadIdx.x;  // 1024 cols x 128 octets
        int n = t & 1023;
        int k = (t >> 10) << 3;
        u16x8 hv, lv;
        #pragma unroll
        for (int j = 0; j < 8; ++j) {
            float x = W[((size_t)(k + j) << 10) + n];
            unsigned short h = f2bf(x);
            hv[j] = h;
            lv[j] = f2bf(x - bf2f(h));
        }
        int cb = n >> 7, nr = n & 127, kt = k >> 5, s = (k >> 3) & 3;
        char* base = Bimg + (((size_t)(cb * 32 + kt)) << 14) + nr * 128;
        *reinterpret_cast<u16x8*>(base + ((s ^ (nr & 7)) << 4)) = hv;
        *reinterpret_cast<u16x8*>(base + (((s + 4) ^ (nr & 7)) << 4)) = lv;
    }
}

// ---------------- GEMM1: 128x128 tile, 4 waves (2x2 of 64x64), BK=32 ----------------
#define MFMA_B16 __builtin_amdgcn_mfma_f32_16x16x32_bf16

__global__ __launch_bounds__(256, 3) void gemm1_mfma_kernel(
    const char* __restrict__ Aimg, const char* __restrict__ Bimg,
    const float* __restrict__ bias, float* __restrict__ Hout)
{
    __shared__ char As[16384];
    __shared__ char Bs[16384];

    int bid = blockIdx.x;
    // XCD-aware bijective swizzle: 512 blocks, 8 XCDs, 64 consecutive per XCD
    int swz = (bid & 7) * 64 + (bid >> 3);
    int rb = swz >> 3;          // 0..63
    int cb = swz & 7;           // 0..7

    int tid = threadIdx.x;
    int lane = tid & 63;
    int wave = tid >> 6;
    int wm = (wave >> 1) * 64;
    int wn = (wave & 1) * 64;
    int l15 = lane & 15, l4 = lane >> 4;

    // precomputed swizzled fragment offsets (constant across K-tiles)
    int aoff_h[4], aoff_l[4], boff_h[4], boff_l[4];
    #pragma unroll
    for (int f = 0; f < 4; ++f) {
        int ar = wm + f * 16 + l15;
        aoff_h[f] = ar * 128 + ((l4 ^ (ar & 7)) << 4);
        aoff_l[f] = ar * 128 + (((l4 + 4) ^ (ar & 7)) << 4);
        int br = wn + f * 16 + l15;
        boff_h[f] = br * 128 + ((l4 ^ (br & 7)) << 4);
        boff_l[f] = br * 128 + (((l4 + 4) ^ (br & 7)) << 4);
    }

    const char* abase = Aimg + (size_t)rb * (32 * 16384);
    const char* bbase = Bimg + (size_t)cb * (32 * 16384);

    f32x4 acc[4][4];
    #pragma unroll
    for (int i = 0; i < 4; ++i)
        #pragma unroll
        for (int j = 0; j < 4; ++j)
            acc[i][j] = (f32x4){0.f, 0.f, 0.f, 0.f};

    for (int kt = 0; kt < 32; ++kt) {
        const char* ga = abase + (kt << 14);
        const char* gb = bbase + (kt << 14);
        int toff = tid << 4;
        #pragma unroll
        for (int r = 0; r < 4; ++r) {
            gload_lds16(ga + (r << 12) + toff, As + (r << 12) + toff);
            gload_lds16(gb + (r << 12) + toff, Bs + (r << 12) + toff);
        }
        __syncthreads();   // compiler emits vmcnt(0) drain -> tiles ready

        s16x8 ah[4], al[4], bh[4], bl[4];
        #pragma unroll
        for (int f = 0; f < 4; ++f) {
            ah[f] = *reinterpret_cast<const s16x8*>(As + aoff_h[f]);
            al[f] = *reinterpret_cast<const s16x8*>(As + aoff_l[f]);
            bh[f] = *reinterpret_cast<const s16x8*>(Bs + boff_h[f]);
            bl[f] = *reinterpret_cast<const s16x8*>(Bs + boff_l[f]);
        }
        // pass-major ordering: 16 independent MFMAs between same-acc reuses
        #pragma unroll
        for (int m = 0; m < 4; ++m)
            #pragma unroll
            for (int n = 0; n < 4; ++n)
                acc[m][n] = MFMA_B16(ah[m], bh[n], acc[m][n], 0, 0, 0);
        #pragma unroll
        for (int m = 0; m < 4; ++m)
            #pragma unroll
            for (int n = 0; n < 4; ++n)
                acc[m][n] = MFMA_B16(ah[m], bl[n], acc[m][n], 0, 0, 0);
        #pragma unroll
        for (int m = 0; m < 4; ++m)
            #pragma unroll
            for (int n = 0; n < 4; ++n)
                acc[m][n] = MFMA_B16(al[m], bh[n], acc[m][n], 0, 0, 0);
        __syncthreads();   // all waves done reading before next stage overwrites
    }

    // epilogue: bias + relu. C/D map: row=(lane>>4)*4+reg, col=lane&15 (verified)
    int row0 = rb * 128 + wm;
    int col0 = cb * 128 + wn;
    float bcol[4];
    #pragma unroll
    for (int fn = 0; fn < 4; ++fn) bcol[fn] = bias[col0 + fn * 16 + l15];
    #pragma unroll
    for (int fm = 0; fm < 4; ++fm)
        #pragma unroll
        for (int r = 0; r < 4; ++r) {
            int row = row0 + fm * 16 + l4 * 4 + r;
            float* orow = Hout + ((size_t)row << 10);
            #pragma unroll
            for (int fn = 0; fn < 4; ++fn) {
                int col = col0 + fn * 16 + l15;
                orow[col] = fmaxf(acc[fm][fn][r] + bcol[fn], 0.f);
            }
        }
}

// ---------------- R1 fallback fp32 SGEMM (verified) ----------------
#define BM 128
#define BN 128
#define BK 16
#define PAD_LD 132

__global__ __launch_bounds__(256) void gemm1_relu_kernel(
    const float* __restrict__ A, const float* __restrict__ W,
    const float* __restrict__ bias, float* __restrict__ Hout,
    int M, int N, int K)
{
    __shared__ float As[BK][PAD_LD];
    __shared__ float Bs[BK][PAD_LD];
    const int tid = threadIdx.x;
    const int tx = tid & 15;
    const int ty = tid >> 4;
    const int row0 = blockIdx.y * BM;
    const int col0 = blockIdx.x * BN;
    float acc[8][8];
    #pragma unroll
    for (int i = 0; i < 8; ++i)
        #pragma unroll
        for (int j = 0; j < 8; ++j) acc[i][j] = 0.f;
    const int a_row = tid >> 2;
    const int a_k4  = (tid & 3) * 4;
    const int b_col4 = (tid & 31) * 4;
    const int b_kk   = tid >> 5;
    for (int k0 = 0; k0 < K; k0 += BK) {
        #pragma unroll
        for (int half = 0; half < 2; ++half) {
            int r = a_row + half * 64;
            float4 av = *reinterpret_cast<const float4*>(&A[(size_t)(row0 + r) * K + k0 + a_k4]);
            As[a_k4 + 0][r] = av.x; As[a_k4 + 1][r] = av.y;
            As[a_k4 + 2][r] = av.z; As[a_k4 + 3][r] = av.w;
        }
        #pragma unroll
        for (int half = 0; half < 2; ++half) {
            int kk = b_kk + half * 8;
            float4 bv = *reinterpret_cast<const float4*>(&W[(size_t)(k0 + kk) * N + col0 + b_col4]);
            *reinterpret_cast<float4*>(&Bs[kk][b_col4]) = bv;
        }
        __syncthreads();
        #pragma unroll
        for (int k = 0; k < BK; ++k) {
            float4 a0 = *reinterpret_cast<const float4*>(&As[k][ty * 8]);
            float4 a1 = *reinterpret_cast<const float4*>(&As[k][ty * 8 + 4]);
            float4 b0 = *reinterpret_cast<const float4*>(&Bs[k][tx * 8]);
            float4 b1 = *reinterpret_cast<const float4*>(&Bs[k][tx * 8 + 4]);
            float a[8] = {a0.x, a0.y, a0.z, a0.w, a1.x, a1.y, a1.z, a1.w};
            float b[8] = {b0.x, b0.y, b0.z, b0.w, b1.x, b1.y, b1.z, b1.w};
            #pragma unroll
            for (int i = 0; i < 8; ++i)
                #pragma unroll
                for (int j = 0; j < 8; ++j)
                    acc[i][j] = fmaf(a[i], b[j], acc[i][j]);
        }
        __syncthreads();
    }
    #pragma unroll
    for (int i = 0; i < 8; ++i) {
        int row = row0 + ty * 8 + i;
        #pragma unroll
        for (int j4 = 0; j4 < 2; ++j4) {
            int col = col0 + tx * 8 + j4 * 4;
            float4 v;
            v.x = fmaxf(acc[i][j4 * 4 + 0] + bias[col + 0], 0.f);
            v.y = fmaxf(acc[i][j4 * 4 + 1] + bias[col + 1], 0.f);
            v.z = fmaxf(acc[i][j4 * 4 + 2] + bias[col + 2], 0.f);
            v.w = fmaxf(acc[i][j4 * 4 + 3] + bias[col + 3], 0.f);
            *reinterpret_cast<float4*>(&Hout[(size_t)row * N + col]) = v;
        }
    }
}

// ---------------- router + combine (one block per token) ----------------
__global__ __launch_bounds__(256) void route_combine_kernel(
    const float* __restrict__ Hbuf, const float* __restrict__ W2,
    const float* __restrict__ b2, const float* __restrict__ EO,
    float* __restrict__ Out, int M)
{
    const int t = blockIdx.x;
    const int tid = threadIdx.x;
    const int lane = tid & 63;
    const int wave = tid >> 6;
    const float* hrow = Hbuf + (size_t)t * H_DIM;

    float part[E_NUM];
    #pragma unroll
    for (int e = 0; e < E_NUM; ++e) part[e] = 0.f;
    #pragma unroll
    for (int it = 0; it < H_DIM / 256; ++it) {
        int j = tid + it * 256;
        float hv = hrow[j];
        const float* w = W2 + (size_t)j * E_NUM;
        #pragma unroll
        for (int e = 0; e < E_NUM; ++e) part[e] = fmaf(hv, w[e], part[e]);
    }
    #pragma unroll
    for (int off = 32; off > 0; off >>= 1)
        #pragma unroll
        for (int e = 0; e < E_NUM; ++e)
            part[e] += __shfl_down(part[e], off, 64);

    __shared__ float sred[4][E_NUM];
    __shared__ float s_g[2];
    __shared__ int   s_e[2];
    if (lane == 0)
        #pragma unroll
        for (int e = 0; e < E_NUM; ++e) sred[wave][e] = part[e];
    __syncthreads();

    if (tid == 0) {
        float logits[E_NUM];
        #pragma unroll
        for (int e = 0; e < E_NUM; ++e)
            logits[e] = sred[0][e] + sred[1][e] + sred[2][e] + sred[3][e] + b2[e];
        float m = logits[0];
        #pragma unroll
        for (int e = 1; e < E_NUM; ++e) m = fmaxf(m, logits[e]);
        float p[E_NUM], ssum = 0.f;
        #pragma unroll
        for (int e = 0; e < E_NUM; ++e) { p[e] = expf(logits[e] - m); ssum += p[e]; }
        float inv = 1.f / ssum;
        #pragma unroll
        for (int e = 0; e < E_NUM; ++e) p[e] *= inv;
        int e0 = 0;
        #pragma unroll
        for (int e = 1; e < E_NUM; ++e) if (p[e] > p[e0]) e0 = e;
        int e1 = (e0 == 0) ? 1 : 0;
        #pragma unroll
        for (int e = 0; e < E_NUM; ++e)
            if (e != e0 && e != e1 && p[e] > p[e1]) e1 = e;
        s_g[0] = p[e0]; s_g[1] = p[e1];
        s_e[0] = e0;    s_e[1] = e1;
    }
    __syncthreads();

    const float g0 = s_g[0], g1 = s_g[1];
    const size_t base0 = ((size_t)s_e[0] * M + t) * H_DIM;
    const size_t base1 = ((size_t)s_e[1] * M + t) * H_DIM;
    const int d = tid * 4;
    float4 x0 = *reinterpret_cast<const float4*>(&EO[base0 + d]);
    float4 x1 = *reinterpret_cast<const float4*>(&EO[base1 + d]);
    float4 o;
    o.x = g0 * x0.x + g1 * x1.x;
    o.y = g0 * x0.y + g1 * x1.y;
    o.z = g0 * x0.z + g1 * x1.z;
    o.w = g0 * x0.w + g1 * x1.w;
    *reinterpret_cast<float4*>(&Out[(size_t)t * H_DIM + d]) = o;
}

extern "C" void kernel_launch(void* const* d_in, const int* in_sizes, int n_in,
                              void* d_out, int out_size, void* d_ws, size_t ws_size,
                              hipStream_t stream)
{
    const float* hs = (const float*)d_in[0];
    const float* EO = (const float*)d_in[1];
    const float* W1 = (const float*)d_in[2];
    const float* b1 = (const float*)d_in[3];
    const float* W2 = (const float*)d_in[4];
    const float* b2 = (const float*)d_in[5];

    const int M = in_sizes[0] / H_DIM;   // 8192
    float* out = (float*)d_out;

    const size_t A_IMG = (size_t)64 * 32 * 16384;
    const size_t B_IMG = (size_t)8 * 32 * 16384;
    if (M == 8192 && ws_size >= A_IMG + B_IMG) {
        char* Aimg = (char*)d_ws;
        char* Bimg = (char*)d_ws + A_IMG;
        prep_fused_kernel<<<4096 + 512, 256, 0, stream>>>(hs, W1, Aimg, Bimg);
        gemm1_mfma_kernel<<<512, 256, 0, stream>>>(Aimg, Bimg, b1, out);
    } else {
        dim3 grid1(H_DIM / BN, M / BM);
        gemm1_relu_kernel<<<grid1, 256, 0, stream>>>(hs, W1, b1, out, M, H_DIM, H_DIM);
    }
    route_combine_kernel<<<M, 256, 0, stream>>>(out, W2, b2, EO, out, M);
}

// Round 6
// 82.527 us; speedup vs baseline: 1.1012x; 1.0488x over previous
//
#include <hip/hip_runtime.h>
#include <math.h>

// ExpertGating: h=relu(hs@W1+b1); logits=h@W2+b2; softmax; top-2; combine.
// R6: h is never materialized. GEMM1 epilogue computes partial router logits
// P = relu(acc+b1) @ W2slice via MFMA (h -> LDS bf16 hi/lo, swizzled; 3-pass
// split keeps logit error ~1e-5 so top-2 selection stays exact). Partials
// [cb][M][8] go to ws; combine kernel reduces 8 partials deterministically,
// does softmax/top-2, gathers expert outputs. Main GEMM loop = R5 (verified).

#define H_DIM 1024
#define E_NUM 8

typedef __attribute__((ext_vector_type(8))) short s16x8;
typedef __attribute__((ext_vector_type(8))) unsigned short u16x8;
typedef __attribute__((ext_vector_type(4))) float f32x4;

__device__ __forceinline__ unsigned short f2bf(float x) {
    unsigned int u = __float_as_uint(x);
    unsigned int r = (u + 0x7FFFu + ((u >> 16) & 1u)) >> 16;
    return (unsigned short)r;
}
__device__ __forceinline__ float bf2f(unsigned short b) {
    return __uint_as_float(((unsigned int)b) << 16);
}
__device__ __forceinline__ void gload_lds16(const void* g, void* lds) {
    __builtin_amdgcn_global_load_lds(
        (const __attribute__((address_space(1))) void*)g,
        (__attribute__((address_space(3))) void*)lds, 16, 0, 0);
}

// ---------------- fused prep: hs and W1 -> swizzled hi/lo bf16 images --------
__global__ __launch_bounds__(256) void prep_fused_kernel(
    const float* __restrict__ A, const float* __restrict__ W,
    char* __restrict__ Aimg, char* __restrict__ Bimg)
{
    if (blockIdx.x < 4096) {
        int t = blockIdx.x * 256 + threadIdx.x;   // 8192 rows x 128 octets
        int m = t >> 7;
        int k = (t & 127) << 3;
        const float* src = A + ((size_t)m << 10) + k;
        float4 v0 = *reinterpret_cast<const float4*>(src);
        float4 v1 = *reinterpret_cast<const float4*>(src + 4);
        float xs[8] = {v0.x, v0.y, v0.z, v0.w, v1.x, v1.y, v1.z, v1.w};
        u16x8 hv, lv;
        #pragma unroll
        for (int j = 0; j < 8; ++j) {
            unsigned short h = f2bf(xs[j]);
            hv[j] = h;
            lv[j] = f2bf(xs[j] - bf2f(h));
        }
        int rb = m >> 7, mr = m & 127, kt = k >> 5, s = (k >> 3) & 3;
        char* base = Aimg + (((size_t)(rb * 32 + kt)) << 14) + mr * 128;
        *reinterpret_cast<u16x8*>(base + ((s ^ (mr & 7)) << 4)) = hv;
        *reinterpret_cast<u16x8*>(base + (((s + 4) ^ (mr & 7)) << 4)) = lv;
    } else {
        int t = (blockIdx.x - 4096) * 256 + threadIdx.x;  // 1024 cols x 128 octets
        int n = t & 1023;
        int k = (t >> 10) << 3;
        u16x8 hv, lv;
        #pragma unroll
        for (int j = 0; j < 8; ++j) {
            float x = W[((size_t)(k + j) << 10) + n];
            unsigned short h = f2bf(x);
            hv[j] = h;
            lv[j] = f2bf(x - bf2f(h));
        }
        int cb = n >> 7, nr = n & 127, kt = k >> 5, s = (k >> 3) & 3;
        char* base = Bimg + (((size_t)(cb * 32 + kt)) << 14) + nr * 128;
        *reinterpret_cast<u16x8*>(base + ((s ^ (nr & 7)) << 4)) = hv;
        *reinterpret_cast<u16x8*>(base + (((s + 4) ^ (nr & 7)) << 4)) = lv;
    }
}

// ---------------- GEMM1 + fused router logits ----------------
// LDS map: [0,16384)=As / h_hi[128][64]; [16384,32768)=Bs / h_lo[128][64];
//          [32768,39296)=w2t 24 rows x 272B (rows 0-7 hi, 8-15 lo, 16-23 zero)
#define MFMA_B16 __builtin_amdgcn_mfma_f32_16x16x32_bf16
#define W2T_OFS 32768
#define W2T_PITCH 272

__global__ __launch_bounds__(256, 3) void gemm1_logits_kernel(
    const char* __restrict__ Aimg, const char* __restrict__ Bimg,
    const float* __restrict__ bias, const float* __restrict__ W2,
    float* __restrict__ Plog)
{
    __shared__ char smem[39296];

    int bid = blockIdx.x;
    int swz = (bid & 7) * 64 + (bid >> 3);   // bijective, 512 % 8 == 0
    int rb = swz >> 3;          // 0..63
    int cb = swz & 7;           // 0..7

    int tid = threadIdx.x;
    int lane = tid & 63;
    int wave = tid >> 6;
    int wm = (wave >> 1) * 64;
    int wn = (wave & 1) * 64;
    int l15 = lane & 15, l4 = lane >> 4;

    // ---- w2t: zero, then fill hi/lo bf16 of W2 slice (transposed) ----
    const int col0g = cb * 128;
    for (int i = tid; i < 1632; i += 256)
        *reinterpret_cast<float*>(smem + W2T_OFS + i * 4) = 0.f;
    __syncthreads();
    {
        int e = tid & 7, c4 = tid >> 3;   // c4: 0..31
        #pragma unroll
        for (int j = 0; j < 4; ++j) {
            int col = c4 * 4 + j;
            float w = W2[(size_t)(col0g + col) * E_NUM + e];
            unsigned short wh = f2bf(w);
            unsigned short wl = f2bf(w - bf2f(wh));
            *reinterpret_cast<unsigned short*>(smem + W2T_OFS + e * W2T_PITCH + col * 2) = wh;
            *reinterpret_cast<unsigned short*>(smem + W2T_OFS + (e + 8) * W2T_PITCH + col * 2) = wl;
        }
    }
    __syncthreads();

    // fragment LDS offsets (swizzle baked in), constant across K-tiles
    int aoff_h[4], aoff_l[4], boff_h[4], boff_l[4];
    #pragma unroll
    for (int f = 0; f < 4; ++f) {
        int ar = wm + f * 16 + l15;
        aoff_h[f] = ar * 128 + ((l4 ^ (ar & 7)) << 4);
        aoff_l[f] = ar * 128 + (((l4 + 4) ^ (ar & 7)) << 4);
        int br = wn + f * 16 + l15;
        boff_h[f] = 16384 + br * 128 + ((l4 ^ (br & 7)) << 4);
        boff_l[f] = 16384 + br * 128 + (((l4 + 4) ^ (br & 7)) << 4);
    }

    const char* abase = Aimg + (size_t)rb * (32 * 16384);
    const char* bbase = Bimg + (size_t)cb * (32 * 16384);

    f32x4 acc[4][4];
    #pragma unroll
    for (int i = 0; i < 4; ++i)
        #pragma unroll
        for (int j = 0; j < 4; ++j)
            acc[i][j] = (f32x4){0.f, 0.f, 0.f, 0.f};

    for (int kt = 0; kt < 32; ++kt) {
        const char* ga = abase + (kt << 14);
        const char* gb = bbase + (kt << 14);
        int toff = tid << 4;
        #pragma unroll
        for (int r = 0; r < 4; ++r) {
            gload_lds16(ga + (r << 12) + toff, smem + (r << 12) + toff);
            gload_lds16(gb + (r << 12) + toff, smem + 16384 + (r << 12) + toff);
        }
        __syncthreads();

        s16x8 ah[4], al[4], bh[4], bl[4];
        #pragma unroll
        for (int f = 0; f < 4; ++f) {
            ah[f] = *reinterpret_cast<const s16x8*>(smem + aoff_h[f]);
            al[f] = *reinterpret_cast<const s16x8*>(smem + aoff_l[f]);
            bh[f] = *reinterpret_cast<const s16x8*>(smem + boff_h[f]);
            bl[f] = *reinterpret_cast<const s16x8*>(smem + boff_l[f]);
        }
        #pragma unroll
        for (int m = 0; m < 4; ++m)
            #pragma unroll
            for (int n = 0; n < 4; ++n)
                acc[m][n] = MFMA_B16(ah[m], bh[n], acc[m][n], 0, 0, 0);
        #pragma unroll
        for (int m = 0; m < 4; ++m)
            #pragma unroll
            for (int n = 0; n < 4; ++n)
                acc[m][n] = MFMA_B16(ah[m], bl[n], acc[m][n], 0, 0, 0);
        #pragma unroll
        for (int m = 0; m < 4; ++m)
            #pragma unroll
            for (int n = 0; n < 4; ++n)
                acc[m][n] = MFMA_B16(al[m], bh[n], acc[m][n], 0, 0, 0);
        __syncthreads();
    }

    // ---- fused epilogue: P[row][e] = relu(acc + b1) @ W2slice, 3-pass split ----
    float bcol[4];
    #pragma unroll
    for (int fn = 0; fn < 4; ++fn) bcol[fn] = bias[col0g + wn + fn * 16 + l15];

    f32x4 plog[2];
    plog[0] = (f32x4){0.f, 0.f, 0.f, 0.f};
    plog[1] = (f32x4){0.f, 0.f, 0.f, 0.f};

    #pragma unroll
    for (int ch = 0; ch < 2; ++ch) {
        // waves owning col-half ch write h hi/lo (swizzled) into As/Bs region
        if ((wave & 1) == ch) {
            #pragma unroll
            for (int fm = 0; fm < 4; ++fm)
                #pragma unroll
                for (int r = 0; r < 4; ++r) {
                    int row = wm + fm * 16 + l4 * 4 + r;
                    int rx = (row & 7) << 4;
                    #pragma unroll
                    for (int fn = 0; fn < 4; ++fn) {
                        float hv = fmaxf(acc[fm][fn][r] + bcol[fn], 0.f);
                        unsigned short hh = f2bf(hv);
                        unsigned short hl = f2bf(hv - bf2f(hh));
                        int byteoff = row * 128 + ((((fn * 16 + l15) * 2)) ^ rx);
                        *reinterpret_cast<unsigned short*>(smem + byteoff) = hh;
                        *reinterpret_cast<unsigned short*>(smem + 16384 + byteoff) = hl;
                    }
                }
        }
        __syncthreads();

        // all waves: logits MFMA over this 64-col half (K chunks kc=0,1)
        #pragma unroll
        for (int fmm = 0; fmm < 2; ++fmm) {
            int rowb = wave * 32 + fmm * 16 + l15;
            int rx = (rowb & 7) << 4;
            int rowbase = rowb * 128;
            #pragma unroll
            for (int kc = 0; kc < 2; ++kc) {
                int co = kc * 64 + l4 * 16;
                s16x8 ahi = *reinterpret_cast<const s16x8*>(smem + rowbase + (co ^ rx));
                s16x8 alo = *reinterpret_cast<const s16x8*>(smem + 16384 + rowbase + (co ^ rx));
                int wb = W2T_OFS + ch * 128 + kc * 64 + l4 * 16;
                s16x8 whi = *reinterpret_cast<const s16x8*>(smem + wb + l15 * W2T_PITCH);
                s16x8 wlo = *reinterpret_cast<const s16x8*>(smem + wb + (l15 + 8) * W2T_PITCH);
                plog[fmm] = MFMA_B16(ahi, whi, plog[fmm], 0, 0, 0);
                plog[fmm] = MFMA_B16(ahi, wlo, plog[fmm], 0, 0, 0);
                plog[fmm] = MFMA_B16(alo, whi, plog[fmm], 0, 0, 0);
            }
        }
        __syncthreads();
    }

    // store partials: P rows = rb*128 + wave*32 + fmm*16 + l4*4 + r, expert = l15
    if (l15 < 8) {
        #pragma unroll
        for (int fmm = 0; fmm < 2; ++fmm) {
            int rowg = rb * 128 + wave * 32 + fmm * 16 + l4 * 4;
            #pragma unroll
            for (int r = 0; r < 4; ++r)
                Plog[((size_t)cb * 8192 + rowg + r) * E_NUM + l15] = plog[fmm][r];
        }
    }
}

// ---------------- combine: reduce partials -> softmax -> top2 -> gather ------
__global__ __launch_bounds__(256) void route_combine2_kernel(
    const float* __restrict__ Plog, const float* __restrict__ b2,
    const float* __restrict__ EO, float* __restrict__ Out, int M)
{
    const int t = blockIdx.x;
    const int tid = threadIdx.x;

    __shared__ float s_logit[E_NUM];
    __shared__ float s_g[2];
    __shared__ int   s_e[2];

    if (tid < 64) {
        int cbi = tid >> 3, e = tid & 7;
        float v = Plog[((size_t)cbi * M + t) * E_NUM + e];
        v += __shfl_xor(v, 8, 64);
        v += __shfl_xor(v, 16, 64);
        v += __shfl_xor(v, 32, 64);
        if (tid < 8) s_logit[tid] = v + b2[tid];
    }
    __syncthreads();

    if (tid == 0) {
        float logits[E_NUM];
        #pragma unroll
        for (int e = 0; e < E_NUM; ++e) logits[e] = s_logit[e];
        float m = logits[0];
        #pragma unroll
        for (int e = 1; e < E_NUM; ++e) m = fmaxf(m, logits[e]);
        float p[E_NUM], ssum = 0.f;
        #pragma unroll
        for (int e = 0; e < E_NUM; ++e) { p[e] = expf(logits[e] - m); ssum += p[e]; }
        float inv = 1.f / ssum;
        #pragma unroll
        for (int e = 0; e < E_NUM; ++e) p[e] *= inv;
        int e0 = 0;
        #pragma unroll
        for (int e = 1; e < E_NUM; ++e) if (p[e] > p[e0]) e0 = e;
        int e1 = (e0 == 0) ? 1 : 0;
        #pragma unroll
        for (int e = 0; e < E_NUM; ++e)
            if (e != e0 && e != e1 && p[e] > p[e1]) e1 = e;
        s_g[0] = p[e0]; s_g[1] = p[e1];
        s_e[0] = e0;    s_e[1] = e1;
    }
    __syncthreads();

    const float g0 = s_g[0], g1 = s_g[1];
    const size_t base0 = ((size_t)s_e[0] * M + t) * H_DIM;
    const size_t base1 = ((size_t)s_e[1] * M + t) * H_DIM;
    const int d = tid * 4;
    float4 x0 = *reinterpret_cast<const float4*>(&EO[base0 + d]);
    float4 x1 = *reinterpret_cast<const float4*>(&EO[base1 + d]);
    float4 o;
    o.x = g0 * x0.x + g1 * x1.x;
    o.y = g0 * x0.y + g1 * x1.y;
    o.z = g0 * x0.z + g1 * x1.z;
    o.w = g0 * x0.w + g1 * x1.w;
    *reinterpret_cast<float4*>(&Out[(size_t)t * H_DIM + d]) = o;
}

// ---------------- R1 fallback fp32 SGEMM + old combine (verified) ----------------
#define BM 128
#define BN 128
#define BK 16
#define PAD_LD 132

__global__ __launch_bounds__(256) void gemm1_relu_kernel(
    const float* __restrict__ A, const float* __restrict__ W,
    const float* __restrict__ bias, float* __restrict__ Hout,
    int M, int N, int K)
{
    __shared__ float As[BK][PAD_LD];
    __shared__ float Bs[BK][PAD_LD];
    const int tid = threadIdx.x;
    const int tx = tid & 15;
    const int ty = tid >> 4;
    const int row0 = blockIdx.y * BM;
    const int col0 = blockIdx.x * BN;
    float acc[8][8];
    #pragma unroll
    for (int i = 0; i < 8; ++i)
        #pragma unroll
        for (int j = 0; j < 8; ++j) acc[i][j] = 0.f;
    const int a_row = tid >> 2;
    const int a_k4  = (tid & 3) * 4;
    const int b_col4 = (tid & 31) * 4;
    const int b_kk   = tid >> 5;
    for (int k0 = 0; k0 < K; k0 += BK) {
        #pragma unroll
        for (int half = 0; half < 2; ++half) {
            int r = a_row + half * 64;
            float4 av = *reinterpret_cast<const float4*>(&A[(size_t)(row0 + r) * K + k0 + a_k4]);
            As[a_k4 + 0][r] = av.x; As[a_k4 + 1][r] = av.y;
            As[a_k4 + 2][r] = av.z; As[a_k4 + 3][r] = av.w;
        }
        #pragma unroll
        for (int half = 0; half < 2; ++half) {
            int kk = b_kk + half * 8;
            float4 bv = *reinterpret_cast<const float4*>(&W[(size_t)(k0 + kk) * N + col0 + b_col4]);
            *reinterpret_cast<float4*>(&Bs[kk][b_col4]) = bv;
        }
        __syncthreads();
        #pragma unroll
        for (int k = 0; k < BK; ++k) {
            float4 a0 = *reinterpret_cast<const float4*>(&As[k][ty * 8]);
            float4 a1 = *reinterpret_cast<const float4*>(&As[k][ty * 8 + 4]);
            float4 b0 = *reinterpret_cast<const float4*>(&Bs[k][tx * 8]);
            float4 b1 = *reinterpret_cast<const float4*>(&Bs[k][tx * 8 + 4]);
            float a[8] = {a0.x, a0.y, a0.z, a0.w, a1.x, a1.y, a1.z, a1.w};
            float b[8] = {b0.x, b0.y, b0.z, b0.w, b1.x, b1.y, b1.z, b1.w};
            #pragma unroll
            for (int i = 0; i < 8; ++i)
                #pragma unroll
                for (int j = 0; j < 8; ++j)
                    acc[i][j] = fmaf(a[i], b[j], acc[i][j]);
        }
        __syncthreads();
    }
    #pragma unroll
    for (int i = 0; i < 8; ++i) {
        int row = row0 + ty * 8 + i;
        #pragma unroll
        for (int j4 = 0; j4 < 2; ++j4) {
            int col = col0 + tx * 8 + j4 * 4;
            float4 v;
            v.x = fmaxf(acc[i][j4 * 4 + 0] + bias[col + 0], 0.f);
            v.y = fmaxf(acc[i][j4 * 4 + 1] + bias[col + 1], 0.f);
            v.z = fmaxf(acc[i][j4 * 4 + 2] + bias[col + 2], 0.f);
            v.w = fmaxf(acc[i][j4 * 4 + 3] + bias[col + 3], 0.f);
            *reinterpret_cast<float4*>(&Hout[(size_t)row * N + col]) = v;
        }
    }
}

__global__ __launch_bounds__(256) void route_combine_kernel(
    const float* __restrict__ Hbuf, const float* __restrict__ W2,
    const float* __restrict__ b2, const float* __restrict__ EO,
    float* __restrict__ Out, int M)
{
    const int t = blockIdx.x;
    const int tid = threadIdx.x;
    const int lane = tid & 63;
    const int wave = tid >> 6;
    const float* hrow = Hbuf + (size_t)t * H_DIM;

    float part[E_NUM];
    #pragma unroll
    for (int e = 0; e < E_NUM; ++e) part[e] = 0.f;
    #pragma unroll
    for (int it = 0; it < H_DIM / 256; ++it) {
        int j = tid + it * 256;
        float hv = hrow[j];
        const float* w = W2 + (size_t)j * E_NUM;
        #pragma unroll
        for (int e = 0; e < E_NUM; ++e) part[e] = fmaf(hv, w[e], part[e]);
    }
    #pragma unroll
    for (int off = 32; off > 0; off >>= 1)
        #pragma unroll
        for (int e = 0; e < E_NUM; ++e)
            part[e] += __shfl_down(part[e], off, 64);

    __shared__ float sred[4][E_NUM];
    __shared__ float s_g[2];
    __shared__ int   s_e[2];
    if (lane == 0)
        #pragma unroll
        for (int e = 0; e < E_NUM; ++e) sred[wave][e] = part[e];
    __syncthreads();

    if (tid == 0) {
        float logits[E_NUM];
        #pragma unroll
        for (int e = 0; e < E_NUM; ++e)
            logits[e] = sred[0][e] + sred[1][e] + sred[2][e] + sred[3][e] + b2[e];
        float m = logits[0];
        #pragma unroll
        for (int e = 1; e < E_NUM; ++e) m = fmaxf(m, logits[e]);
        float p[E_NUM], ssum = 0.f;
        #pragma unroll
        for (int e = 0; e < E_NUM; ++e) { p[e] = expf(logits[e] - m); ssum += p[e]; }
        float inv = 1.f / ssum;
        #pragma unroll
        for (int e = 0; e < E_NUM; ++e) p[e] *= inv;
        int e0 = 0;
        #pragma unroll
        for (int e = 1; e < E_NUM; ++e) if (p[e] > p[e0]) e0 = e;
        int e1 = (e0 == 0) ? 1 : 0;
        #pragma unroll
        for (int e = 0; e < E_NUM; ++e)
            if (e != e0 && e != e1 && p[e] > p[e1]) e1 = e;
        s_g[0] = p[e0]; s_g[1] = p[e1];
        s_e[0] = e0;    s_e[1] = e1;
    }
    __syncthreads();

    const float g0 = s_g[0], g1 = s_g[1];
    const size_t base0 = ((size_t)s_e[0] * M + t) * H_DIM;
    const size_t base1 = ((size_t)s_e[1] * M + t) * H_DIM;
    const int d = tid * 4;
    float4 x0 = *reinterpret_cast<const float4*>(&EO[base0 + d]);
    float4 x1 = *reinterpret_cast<const float4*>(&EO[base1 + d]);
    float4 o;
    o.x = g0 * x0.x + g1 * x1.x;
    o.y = g0 * x0.y + g1 * x1.y;
    o.z = g0 * x0.z + g1 * x1.z;
    o.w = g0 * x0.w + g1 * x1.w;
    *reinterpret_cast<float4*>(&Out[(size_t)t * H_DIM + d]) = o;
}

extern "C" void kernel_launch(void* const* d_in, const int* in_sizes, int n_in,
                              void* d_out, int out_size, void* d_ws, size_t ws_size,
                              hipStream_t stream)
{
    const float* hs = (const float*)d_in[0];
    const float* EO = (const float*)d_in[1];
    const float* W1 = (const float*)d_in[2];
    const float* b1 = (const float*)d_in[3];
    const float* W2 = (const float*)d_in[4];
    const float* b2 = (const float*)d_in[5];

    const int M = in_sizes[0] / H_DIM;   // 8192
    float* out = (float*)d_out;

    const size_t A_IMG = (size_t)64 * 32 * 16384;       // 33,554,432
    const size_t B_IMG = (size_t)8 * 32 * 16384;        //  4,194,304
    const size_t PART  = (size_t)8 * 8192 * 8 * 4;      //  2,097,152
    if (M == 8192 && ws_size >= A_IMG + B_IMG + PART) {
        char*  Aimg = (char*)d_ws;
        char*  Bimg = (char*)d_ws + A_IMG;
        float* Plog = (float*)((char*)d_ws + A_IMG + B_IMG);
        prep_fused_kernel<<<4096 + 512, 256, 0, stream>>>(hs, W1, Aimg, Bimg);
        gemm1_logits_kernel<<<512, 256, 0, stream>>>(Aimg, Bimg, b1, W2, Plog);
        route_combine2_kernel<<<M, 256, 0, stream>>>(Plog, b2, EO, out, M);
    } else {
        dim3 grid1(H_DIM / BN, M / BM);
        gemm1_relu_kernel<<<grid1, 256, 0, stream>>>(hs, W1, b1, out, M, H_DIM, H_DIM);
        route_combine_kernel<<<M, 256, 0, stream>>>(out, W2, b2, EO, out, M);
    }
}